// Round 1
// baseline (577.042 us; speedup 1.0000x reference)
//
#include <hip/hip_runtime.h>
#include <hip/hip_bf16.h>
#include <stdint.h>
#include <stddef.h>

typedef _Float16 f16;
typedef _Float16 f16x4 __attribute__((ext_vector_type(4)));
typedef _Float16 f16x8 __attribute__((ext_vector_type(8)));
typedef float    f32x4 __attribute__((ext_vector_type(4)));

// ---------------------------------------------------------------------------
// async global->LDS, 16B per lane. LDS dest = wave-uniform base + lane*16.
// ---------------------------------------------------------------------------
__device__ __forceinline__ void gload16(const void* g, void* l) {
  __builtin_amdgcn_global_load_lds(
      (__attribute__((address_space(1))) void*)g,
      (__attribute__((address_space(3))) void*)l,
      16, 0, 0);
}

// ---------------------------------------------------------------------------
// Kernel 1: per-row W prep.  sgn[o,d] = sign(W[o,d]-mean_o) (fp16),
// alpha[o] = mean(|W[o,d]-mean_o|) (fp32).  One 256-thread block per row,
// row (4096 f32 = 16KB) held in registers; coalesced float4 loads.
// ---------------------------------------------------------------------------
__global__ __launch_bounds__(256) void prep_w_kernel(
    const float* __restrict__ W, f16* __restrict__ sgn,
    float* __restrict__ alpha, int K)
{
  const int row = blockIdx.x;
  const int tid = threadIdx.x;
  const float4* Wr = (const float4*)(W + (size_t)row * K);

  float4 v[4];
#pragma unroll
  for (int j = 0; j < 4; ++j) v[j] = Wr[j * 256 + tid];

  __shared__ float red1[4];
  __shared__ float red2[4];

  float s = 0.f;
#pragma unroll
  for (int j = 0; j < 4; ++j) s += (v[j].x + v[j].y) + (v[j].z + v[j].w);
#pragma unroll
  for (int m = 32; m >= 1; m >>= 1) s += __shfl_xor(s, m);
  if ((tid & 63) == 0) red1[tid >> 6] = s;
  __syncthreads();
  const float mean = (red1[0] + red1[1] + red1[2] + red1[3]) * (1.0f / 4096.0f);

  float a = 0.f;
#pragma unroll
  for (int j = 0; j < 4; ++j) {
    a += fabsf(v[j].x - mean) + fabsf(v[j].y - mean) +
         fabsf(v[j].z - mean) + fabsf(v[j].w - mean);
  }
#pragma unroll
  for (int m = 32; m >= 1; m >>= 1) a += __shfl_xor(a, m);
  if ((tid & 63) == 0) red2[tid >> 6] = a;

  f16x4* so = (f16x4*)(sgn + (size_t)row * K);
#pragma unroll
  for (int j = 0; j < 4; ++j) {
    float w0 = v[j].x - mean, w1 = v[j].y - mean,
          w2 = v[j].z - mean, w3 = v[j].w - mean;
    f16x4 o;
    o[0] = (f16)((w0 > 0.f) ? 1.f : ((w0 < 0.f) ? -1.f : 0.f));
    o[1] = (f16)((w1 > 0.f) ? 1.f : ((w1 < 0.f) ? -1.f : 0.f));
    o[2] = (f16)((w2 > 0.f) ? 1.f : ((w2 < 0.f) ? -1.f : 0.f));
    o[3] = (f16)((w3 > 0.f) ? 1.f : ((w3 < 0.f) ? -1.f : 0.f));
    so[j * 256 + tid] = o;
  }
  __syncthreads();
  if (tid == 0)
    alpha[row] = (red2[0] + red2[1] + red2[2] + red2[3]) * (1.0f / 4096.0f);
}

// ---------------------------------------------------------------------------
// Kernel 2: group-64 absmax fake-quantize of x -> fp16.
// One float4 per thread; a 64-elem group = 16 consecutive lanes; absmax via
// __shfl_xor(1,2,4,8). Matches jnp exactly: round-half-even, clip, op order.
// ---------------------------------------------------------------------------
__global__ __launch_bounds__(256) void quant_x_kernel(
    const float4* __restrict__ x4, f16x4* __restrict__ xq4)
{
  const int i = blockIdx.x * 256 + threadIdx.x;
  float4 v = x4[i];
  float am = fmaxf(fmaxf(fabsf(v.x), fabsf(v.y)),
                   fmaxf(fabsf(v.z), fabsf(v.w)));
  am = fmaxf(am, __shfl_xor(am, 1));
  am = fmaxf(am, __shfl_xor(am, 2));
  am = fmaxf(am, __shfl_xor(am, 4));
  am = fmaxf(am, __shfl_xor(am, 8));
  const float scale = fmaxf(am, 1e-8f);

  float q0 = fminf(fmaxf(rintf(v.x / scale * 127.0f), -127.0f), 127.0f);
  float q1 = fminf(fmaxf(rintf(v.y / scale * 127.0f), -127.0f), 127.0f);
  float q2 = fminf(fmaxf(rintf(v.z / scale * 127.0f), -127.0f), 127.0f);
  float q3 = fminf(fmaxf(rintf(v.w / scale * 127.0f), -127.0f), 127.0f);

  f16x4 o;
  o[0] = (f16)(q0 * scale / 127.0f);
  o[1] = (f16)(q1 * scale / 127.0f);
  o[2] = (f16)(q2 * scale / 127.0f);
  o[3] = (f16)(q3 * scale / 127.0f);
  xq4[i] = o;
}

// ---------------------------------------------------------------------------
// Kernel 3: GEMM  C[m,n] = alpha[n] * sum_k A[m,k]*Bt[n,k]
// m97-structure: 128x128 tile, BK=32, 4 waves (2x2), 4x4 16x16x32_f16 frags,
// global_load_lds width 16, linear LDS, 2 barriers per K-step.
// ---------------------------------------------------------------------------
#define BM 128
#define BN 128
#define BK 32

__global__ __launch_bounds__(256) void gemm_kernel(
    const f16* __restrict__ A,   // [M,K] xq
    const f16* __restrict__ Bt,  // [N,K] sgn
    const float* __restrict__ alpha,  // [N]
    float* __restrict__ C, int M, int N, int K)
{
  __shared__ __align__(16) f16 As[BM * BK];  // 8 KB
  __shared__ __align__(16) f16 Bs[BN * BK];  // 8 KB

  const int tid  = threadIdx.x;
  const int wave = tid >> 6;
  const int lane = tid & 63;
  const int bm = blockIdx.y * BM;
  const int bn = blockIdx.x * BN;
  const int wr = (wave >> 1) * 64;   // wave row offset in tile
  const int wc = (wave & 1) * 64;    // wave col offset in tile

  // staging map: thread t -> LDS byte t*16 (rows t/4, col-elems (t%4)*8)
  const int srow = tid >> 2;
  const int scol = (tid & 3) * 8;
  const f16* Ag0 = A  + (size_t)(bm + srow) * K + scol;
  const f16* Ag1 = A  + (size_t)(bm + 64 + srow) * K + scol;
  const f16* Bg0 = Bt + (size_t)(bn + srow) * K + scol;
  const f16* Bg1 = Bt + (size_t)(bn + 64 + srow) * K + scol;

  char* lA0 = (char*)As + wave * 1024;          // wave-uniform LDS bases
  char* lA1 = (char*)As + 4096 + wave * 1024;
  char* lB0 = (char*)Bs + wave * 1024;
  char* lB1 = (char*)Bs + 4096 + wave * 1024;

  const int lrow = lane & 15;
  const int lko  = (lane >> 4) * 8;

  f32x4 acc[4][4] = {};

  const int nk = K / BK;
  for (int kt = 0; kt < nk; ++kt) {
    const int ko = kt * BK;
    gload16(Ag0 + ko, lA0);
    gload16(Ag1 + ko, lA1);
    gload16(Bg0 + ko, lB0);
    gload16(Bg1 + ko, lB1);
    __syncthreads();  // compiler drains vmcnt before s_barrier

    f16x8 af[4], bf[4];
#pragma unroll
    for (int mi = 0; mi < 4; ++mi)
      af[mi] = *(const f16x8*)&As[(wr + mi * 16 + lrow) * BK + lko];
#pragma unroll
    for (int ni = 0; ni < 4; ++ni)
      bf[ni] = *(const f16x8*)&Bs[(wc + ni * 16 + lrow) * BK + lko];

#pragma unroll
    for (int mi = 0; mi < 4; ++mi)
#pragma unroll
      for (int ni = 0; ni < 4; ++ni)
        acc[mi][ni] = __builtin_amdgcn_mfma_f32_16x16x32_f16(
            af[mi], bf[ni], acc[mi][ni], 0, 0, 0);
    __syncthreads();  // all waves done reading before next stage
  }

  // epilogue: C[m,n] = acc * alpha[n];  C/D layout col=lane&15, row=(lane>>4)*4+r
  const int crow = bm + wr + ((lane >> 4) << 2);
  const int ccol = bn + wc + (lane & 15);
#pragma unroll
  for (int ni = 0; ni < 4; ++ni) {
    const int n = ccol + ni * 16;
    const float al = alpha[n];
#pragma unroll
    for (int mi = 0; mi < 4; ++mi) {
#pragma unroll
      for (int r = 0; r < 4; ++r) {
        C[(size_t)(crow + mi * 16 + r) * N + n] = acc[mi][ni][r] * al;
      }
    }
  }
}

// ---------------------------------------------------------------------------
extern "C" void kernel_launch(void* const* d_in, const int* in_sizes, int n_in,
                              void* d_out, int out_size, void* d_ws, size_t ws_size,
                              hipStream_t stream) {
  const float* x = (const float*)d_in[0];  // [M, K] fp32 (flattened [4,2048,4096])
  const float* W = (const float*)d_in[1];  // [N, K] fp32
  float* y = (float*)d_out;                // [M, N] fp32

  const int K = 4096;                      // D_IN (fixed by reference)
  const int M = in_sizes[0] / K;           // 8192
  const int N = in_sizes[1] / K;           // 4096

  // workspace layout (16B-aligned)
  f16*   xq    = (f16*)d_ws;                                   // M*K*2 bytes
  f16*   sgn   = (f16*)((char*)d_ws + (size_t)M * K * 2);      // N*K*2 bytes
  float* alpha = (float*)((char*)d_ws + (size_t)M * K * 2 + (size_t)N * K * 2);

  // 1) W -> sgn, alpha
  prep_w_kernel<<<N, 256, 0, stream>>>(W, sgn, alpha, K);

  // 2) x -> xq (group-64 absmax fake-quant, fp16)
  const int n4 = (M * K) / 4;
  quant_x_kernel<<<n4 / 256, 256, 0, stream>>>((const float4*)x, (f16x4*)xq);

  // 3) GEMM + alpha epilogue
  dim3 grid(N / BN, M / BM);
  gemm_kernel<<<grid, 256, 0, stream>>>(xq, sgn, alpha, y, M, N, K);
}

// Round 2
// 505.887 us; speedup vs baseline: 1.1407x; 1.1407x over previous
//
#include <hip/hip_runtime.h>
#include <hip/hip_bf16.h>
#include <stdint.h>
#include <stddef.h>

typedef _Float16 f16;
typedef _Float16 f16x4 __attribute__((ext_vector_type(4)));
typedef _Float16 f16x8 __attribute__((ext_vector_type(8)));
typedef float    f32x4 __attribute__((ext_vector_type(4)));

// async global->LDS, 16B per lane. LDS dest = wave-uniform base + lane*16.
__device__ __forceinline__ void gload16(const void* g, void* l) {
  __builtin_amdgcn_global_load_lds(
      (__attribute__((address_space(1))) void*)g,
      (__attribute__((address_space(3))) void*)l,
      16, 0, 0);
}

// raw barrier with compiler memory fences (no vmcnt(0) drain, unlike __syncthreads)
__device__ __forceinline__ void BAR() {
  asm volatile("" ::: "memory");
  __builtin_amdgcn_s_barrier();
  asm volatile("" ::: "memory");
}

// ---------------------------------------------------------------------------
// Kernel 1: per-row W prep (unchanged from r1, known-good).
// ---------------------------------------------------------------------------
__global__ __launch_bounds__(256) void prep_w_kernel(
    const float* __restrict__ W, f16* __restrict__ sgn,
    float* __restrict__ alpha, int K)
{
  const int row = blockIdx.x;
  const int tid = threadIdx.x;
  const float4* Wr = (const float4*)(W + (size_t)row * K);

  float4 v[4];
#pragma unroll
  for (int j = 0; j < 4; ++j) v[j] = Wr[j * 256 + tid];

  __shared__ float red1[4];
  __shared__ float red2[4];

  float s = 0.f;
#pragma unroll
  for (int j = 0; j < 4; ++j) s += (v[j].x + v[j].y) + (v[j].z + v[j].w);
#pragma unroll
  for (int m = 32; m >= 1; m >>= 1) s += __shfl_xor(s, m);
  if ((tid & 63) == 0) red1[tid >> 6] = s;
  __syncthreads();
  const float mean = (red1[0] + red1[1] + red1[2] + red1[3]) * (1.0f / 4096.0f);

  float a = 0.f;
#pragma unroll
  for (int j = 0; j < 4; ++j) {
    a += fabsf(v[j].x - mean) + fabsf(v[j].y - mean) +
         fabsf(v[j].z - mean) + fabsf(v[j].w - mean);
  }
#pragma unroll
  for (int m = 32; m >= 1; m >>= 1) a += __shfl_xor(a, m);
  if ((tid & 63) == 0) red2[tid >> 6] = a;

  f16x4* so = (f16x4*)(sgn + (size_t)row * K);
#pragma unroll
  for (int j = 0; j < 4; ++j) {
    float w0 = v[j].x - mean, w1 = v[j].y - mean,
          w2 = v[j].z - mean, w3 = v[j].w - mean;
    f16x4 o;
    o[0] = (f16)((w0 > 0.f) ? 1.f : ((w0 < 0.f) ? -1.f : 0.f));
    o[1] = (f16)((w1 > 0.f) ? 1.f : ((w1 < 0.f) ? -1.f : 0.f));
    o[2] = (f16)((w2 > 0.f) ? 1.f : ((w2 < 0.f) ? -1.f : 0.f));
    o[3] = (f16)((w3 > 0.f) ? 1.f : ((w3 < 0.f) ? -1.f : 0.f));
    so[j * 256 + tid] = o;
  }
  __syncthreads();
  if (tid == 0)
    alpha[row] = (red2[0] + red2[1] + red2[2] + red2[3]) * (1.0f / 4096.0f);
}

// ---------------------------------------------------------------------------
// Kernel 2: group-64 absmax fake-quantize of x -> fp16 (unchanged from r1).
// ---------------------------------------------------------------------------
__global__ __launch_bounds__(256) void quant_x_kernel(
    const float4* __restrict__ x4, f16x4* __restrict__ xq4)
{
  const int i = blockIdx.x * 256 + threadIdx.x;
  float4 v = x4[i];
  float am = fmaxf(fmaxf(fabsf(v.x), fabsf(v.y)),
                   fmaxf(fabsf(v.z), fabsf(v.w)));
  am = fmaxf(am, __shfl_xor(am, 1));
  am = fmaxf(am, __shfl_xor(am, 2));
  am = fmaxf(am, __shfl_xor(am, 4));
  am = fmaxf(am, __shfl_xor(am, 8));
  const float scale = fmaxf(am, 1e-8f);

  float q0 = fminf(fmaxf(rintf(v.x / scale * 127.0f), -127.0f), 127.0f);
  float q1 = fminf(fmaxf(rintf(v.y / scale * 127.0f), -127.0f), 127.0f);
  float q2 = fminf(fmaxf(rintf(v.z / scale * 127.0f), -127.0f), 127.0f);
  float q3 = fminf(fmaxf(rintf(v.w / scale * 127.0f), -127.0f), 127.0f);

  f16x4 o;
  o[0] = (f16)(q0 * scale / 127.0f);
  o[1] = (f16)(q1 * scale / 127.0f);
  o[2] = (f16)(q2 * scale / 127.0f);
  o[3] = (f16)(q3 * scale / 127.0f);
  xq4[i] = o;
}

// ---------------------------------------------------------------------------
// Kernel 3: 256x256 8-phase GEMM (m201 template, plain HIP).
//   C[m,n] = alpha[n] * sum_k A[m,k] * Bt[n,k]
// 8 waves (2M x 4N), BK=64, 128 KiB LDS = 2 tile-buffers x {A0,A1,B0,B1}
// halves of 16 KiB. st_16x32 swizzle: k ^= (row&4)?16:0, applied on the
// pre-swizzled global source (linear gload_lds dest) AND the ds_read addr.
// Counted vmcnt(2) at phases 4/8 only (T4); setprio around MFMA (T5).
// ---------------------------------------------------------------------------
#define BM 256
#define BN 256
#define BK 64

__global__ __launch_bounds__(512, 2) void gemm_kernel(
    const f16* __restrict__ A,        // [M,K] xq
    const f16* __restrict__ Bt,       // [N,K] sgn
    const float* __restrict__ alpha,  // [N]
    float* __restrict__ C, int M, int N, int K)
{
  __shared__ __align__(16) char smem[131072];

  const int tid  = threadIdx.x;
  const int wave = tid >> 6;
  const int lane = tid & 63;
  const int wm = wave >> 2;   // 0..1: which 128-row half of the C tile
  const int wn = wave & 3;    // 0..3: which 64-col strip

  // XCD-aware bijective swizzle (nwg = 512, divisible by 8)
  const int nbx = N / BN;
  const int nwg = gridDim.x;
  const int cpx = nwg >> 3;
  const int bid = blockIdx.x;
  const int swz = (bid & 7) * cpx + (bid >> 3);
  const int bn = (swz % nbx) * BN;
  const int bm = (swz / nbx) * BM;

  // fragment-read addressing (swizzled)
  const int lrow = lane & 15;
  const int lk   = (lane >> 4) * 8;
  const int kxr  = (lane & 4) ? 16 : 0;          // row&4 == lane&4 for frag reads
  const int lko2 = (lk ^ kxr) * 2;
  const int aob  = wm * 16384 + lrow * 128 + lko2;
  const int bob  = 32768 + (wn >> 1) * 16384 + ((wn & 1) * 64 + lrow) * 128 + lko2;

  // staging addressing: lane covers row (l>>3) of an 8-row chunk, 16B of k.
  // pre-swizzle the GLOBAL k so linear LDS holds swizzled content (rule 21).
  const int srow = lane >> 3;
  const int ksrc = ((lane & 7) * 8) ^ ((srow & 4) ? 16 : 0);
  const size_t lsoff = (size_t)srow * K + ksrc;

#define RDA(BUF, mi, kh) (*(const f16x8*)(smem + (BUF) + aob + (mi)*2048 + (kh)*64))
#define RDB(BUF, ni, kh) (*(const f16x8*)(smem + (BUF) + bob + (ni)*2048 + (kh)*64))

  // stage one 128-row x 64-col half-tile: 2 gload16 per wave (16 KiB total)
#define STAGE(LDSOFF, MAT, GROW, T) do {                                        \
    const f16* _s = (MAT) + (size_t)((GROW) + wave * 8) * K + (size_t)(T) * 64; \
    gload16(_s + lsoff, smem + (LDSOFF) + wave * 1024);                         \
    gload16(_s + (size_t)64 * K + lsoff, smem + (LDSOFF) + 8192 + wave * 1024); \
  } while (0)

#define MMQ(AARR, BARR, MBASE) do {                                             \
    _Pragma("unroll")                                                           \
    for (int mi = 0; mi < 4; ++mi) {                                            \
      _Pragma("unroll")                                                         \
      for (int ni = 0; ni < 4; ++ni) {                                          \
        acc[(MBASE) + mi][ni] = __builtin_amdgcn_mfma_f32_16x16x32_f16(         \
            AARR[(MBASE) + mi], BARR[ni], acc[(MBASE) + mi][ni], 0, 0, 0);      \
      }                                                                         \
    }                                                                           \
  } while (0)

  f32x4 acc[8][4] = {};
  f16x8 a0[8], a1[8], bq0[4], bq1[4];

  const int nk = K / BK;  // 64 K-tiles, 2 per iteration

  // prologue: tile0 -> buf0 (4 halves), tile1.B0 -> buf1. vmcnt(2) leaves
  // tile1.B0 in flight = steady-state entry condition.
  STAGE(0,             A,  bm,       0);
  STAGE(16384,         A,  bm + 128, 0);
  STAGE(32768,         Bt, bn,       0);
  STAGE(49152,         Bt, bn + 128, 0);
  STAGE(65536 + 32768, Bt, bn,       1);
  asm volatile("s_waitcnt vmcnt(2)" ::: "memory");
  BAR();

  for (int it = 0; it < nk / 2; ++it) {
    const int t1 = 2 * it + 1;
    int t2 = 2 * it + 2; if (t2 >= nk) t2 -= nk;  // wrapped: harmless overwrite
    int t3 = 2 * it + 3; if (t3 >= nk) t3 -= nk;  // of never-again-read regions

    // ================= tile even (buf0) =================
    // ph1: reads A.k0 (all 8) + B.k0; stage buf1.B1<-t1 (B1 free since prev ph7)
#pragma unroll
    for (int mi = 0; mi < 4; ++mi) a0[mi] = RDA(0, mi, 0);
#pragma unroll
    for (int ni = 0; ni < 4; ++ni) bq0[ni] = RDB(0, ni, 0);
#pragma unroll
    for (int mi = 4; mi < 8; ++mi) a0[mi] = RDA(0, mi, 0);
    STAGE(65536 + 49152, Bt, bn + 128, t1);
    BAR();
    __builtin_amdgcn_s_setprio(1);
    MMQ(a0, bq0, 0);
    __builtin_amdgcn_s_setprio(0);
    BAR();

    // ph2: reads A.k1 lo + B.k1; stage buf1.A0<-t1 (A free since prev ph8)
#pragma unroll
    for (int mi = 0; mi < 4; ++mi) a1[mi] = RDA(0, mi, 1);
#pragma unroll
    for (int ni = 0; ni < 4; ++ni) bq1[ni] = RDB(0, ni, 1);
    STAGE(65536, A, bm, t1);
    BAR();
    __builtin_amdgcn_s_setprio(1);
    MMQ(a0, bq0, 4);
    __builtin_amdgcn_s_setprio(0);
    BAR();

    // ph3: reads A.k1 hi; stage buf1.A1<-t1
#pragma unroll
    for (int mi = 4; mi < 8; ++mi) a1[mi] = RDA(0, mi, 1);
    STAGE(65536 + 16384, A, bm + 128, t1);
    BAR();
    __builtin_amdgcn_s_setprio(1);
    MMQ(a1, bq1, 0);
    __builtin_amdgcn_s_setprio(0);
    BAR();

    // ph4: stage buf0.B0<-t2 (buf0.B reads done by ph3's MFMA waits);
    // counted vmcnt(2): tile1 fully landed, t2.B0 stays in flight.
    STAGE(32768, Bt, bn, t2);
    asm volatile("s_waitcnt vmcnt(2)" ::: "memory");
    BAR();
    __builtin_amdgcn_s_setprio(1);
    MMQ(a1, bq1, 4);
    __builtin_amdgcn_s_setprio(0);
    BAR();

    // ================= tile odd (buf1) =================
    // ph5
#pragma unroll
    for (int mi = 0; mi < 4; ++mi) a0[mi] = RDA(65536, mi, 0);
#pragma unroll
    for (int ni = 0; ni < 4; ++ni) bq0[ni] = RDB(65536, ni, 0);
#pragma unroll
    for (int mi = 4; mi < 8; ++mi) a0[mi] = RDA(65536, mi, 0);
    STAGE(49152, Bt, bn + 128, t2);
    BAR();
    __builtin_amdgcn_s_setprio(1);
    MMQ(a0, bq0, 0);
    __builtin_amdgcn_s_setprio(0);
    BAR();

    // ph6
#pragma unroll
    for (int mi = 0; mi < 4; ++mi) a1[mi] = RDA(65536, mi, 1);
#pragma unroll
    for (int ni = 0; ni < 4; ++ni) bq1[ni] = RDB(65536, ni, 1);
    STAGE(0, A, bm, t2);
    BAR();
    __builtin_amdgcn_s_setprio(1);
    MMQ(a0, bq0, 4);
    __builtin_amdgcn_s_setprio(0);
    BAR();

    // ph7
#pragma unroll
    for (int mi = 4; mi < 8; ++mi) a1[mi] = RDA(65536, mi, 1);
    STAGE(16384, A, bm + 128, t2);
    BAR();
    __builtin_amdgcn_s_setprio(1);
    MMQ(a1, bq1, 0);
    __builtin_amdgcn_s_setprio(0);
    BAR();

    // ph8: stage buf1.B0<-t3; counted vmcnt(2): t2 fully landed.
    STAGE(65536 + 32768, Bt, bn, t3);
    asm volatile("s_waitcnt vmcnt(2)" ::: "memory");
    BAR();
    __builtin_amdgcn_s_setprio(1);
    MMQ(a1, bq1, 4);
    __builtin_amdgcn_s_setprio(0);
    BAR();
  }

  // epilogue: C = acc * alpha[n]; C/D layout col=lane&15, row=(lane>>4)*4+r
  const int r0 = bm + wm * 128 + ((lane >> 4) << 2);
  const int c0 = bn + wn * 64 + (lane & 15);
#pragma unroll
  for (int ni = 0; ni < 4; ++ni) {
    const int n = c0 + ni * 16;
    const float alv = alpha[n];
#pragma unroll
    for (int mi = 0; mi < 8; ++mi) {
#pragma unroll
      for (int r = 0; r < 4; ++r) {
        C[(size_t)(r0 + mi * 16 + r) * N + n] = acc[mi][ni][r] * alv;
      }
    }
  }
}

// ---------------------------------------------------------------------------
extern "C" void kernel_launch(void* const* d_in, const int* in_sizes, int n_in,
                              void* d_out, int out_size, void* d_ws, size_t ws_size,
                              hipStream_t stream) {
  const float* x = (const float*)d_in[0];  // [M, K] fp32
  const float* W = (const float*)d_in[1];  // [N, K] fp32
  float* y = (float*)d_out;                // [M, N] fp32

  const int K = 4096;
  const int M = in_sizes[0] / K;           // 8192
  const int N = in_sizes[1] / K;           // 4096

  f16*   xq    = (f16*)d_ws;
  f16*   sgn   = (f16*)((char*)d_ws + (size_t)M * K * 2);
  float* alpha = (float*)((char*)d_ws + (size_t)M * K * 2 + (size_t)N * K * 2);

  prep_w_kernel<<<N, 256, 0, stream>>>(W, sgn, alpha, K);

  const int n4 = (M * K) / 4;
  quant_x_kernel<<<n4 / 256, 256, 0, stream>>>((const float4*)x, (f16x4*)xq);

  const int nblk = (M / BM) * (N / BN);    // 512, divisible by 8
  gemm_kernel<<<nblk, 512, 0, stream>>>(xq, sgn, alpha, y, M, N, K);
}

// Round 3
// 495.712 us; speedup vs baseline: 1.1641x; 1.0205x over previous
//
#include <hip/hip_runtime.h>
#include <hip/hip_bf16.h>
#include <stdint.h>
#include <stddef.h>

typedef _Float16 f16;
typedef _Float16 f16x4 __attribute__((ext_vector_type(4)));
typedef _Float16 f16x8 __attribute__((ext_vector_type(8)));
typedef float    f32x4 __attribute__((ext_vector_type(4)));

// async global->LDS, 16B per lane. LDS dest = wave-uniform base + lane*16.
__device__ __forceinline__ void gload16(const void* g, void* l) {
  __builtin_amdgcn_global_load_lds(
      (__attribute__((address_space(1))) void*)g,
      (__attribute__((address_space(3))) void*)l,
      16, 0, 0);
}

// raw barrier with compiler memory fences (no vmcnt(0) drain, unlike __syncthreads)
__device__ __forceinline__ void BAR() {
  asm volatile("" ::: "memory");
  __builtin_amdgcn_s_barrier();
  asm volatile("" ::: "memory");
}

// ---------------------------------------------------------------------------
// Kernel 1: per-row W prep (unchanged, known-good).
// ---------------------------------------------------------------------------
__global__ __launch_bounds__(256) void prep_w_kernel(
    const float* __restrict__ W, f16* __restrict__ sgn,
    float* __restrict__ alpha, int K)
{
  const int row = blockIdx.x;
  const int tid = threadIdx.x;
  const float4* Wr = (const float4*)(W + (size_t)row * K);

  float4 v[4];
#pragma unroll
  for (int j = 0; j < 4; ++j) v[j] = Wr[j * 256 + tid];

  __shared__ float red1[4];
  __shared__ float red2[4];

  float s = 0.f;
#pragma unroll
  for (int j = 0; j < 4; ++j) s += (v[j].x + v[j].y) + (v[j].z + v[j].w);
#pragma unroll
  for (int m = 32; m >= 1; m >>= 1) s += __shfl_xor(s, m);
  if ((tid & 63) == 0) red1[tid >> 6] = s;
  __syncthreads();
  const float mean = (red1[0] + red1[1] + red1[2] + red1[3]) * (1.0f / 4096.0f);

  float a = 0.f;
#pragma unroll
  for (int j = 0; j < 4; ++j) {
    a += fabsf(v[j].x - mean) + fabsf(v[j].y - mean) +
         fabsf(v[j].z - mean) + fabsf(v[j].w - mean);
  }
#pragma unroll
  for (int m = 32; m >= 1; m >>= 1) a += __shfl_xor(a, m);
  if ((tid & 63) == 0) red2[tid >> 6] = a;

  f16x4* so = (f16x4*)(sgn + (size_t)row * K);
#pragma unroll
  for (int j = 0; j < 4; ++j) {
    float w0 = v[j].x - mean, w1 = v[j].y - mean,
          w2 = v[j].z - mean, w3 = v[j].w - mean;
    f16x4 o;
    o[0] = (f16)((w0 > 0.f) ? 1.f : ((w0 < 0.f) ? -1.f : 0.f));
    o[1] = (f16)((w1 > 0.f) ? 1.f : ((w1 < 0.f) ? -1.f : 0.f));
    o[2] = (f16)((w2 > 0.f) ? 1.f : ((w2 < 0.f) ? -1.f : 0.f));
    o[3] = (f16)((w3 > 0.f) ? 1.f : ((w3 < 0.f) ? -1.f : 0.f));
    so[j * 256 + tid] = o;
  }
  __syncthreads();
  if (tid == 0)
    alpha[row] = (red2[0] + red2[1] + red2[2] + red2[3]) * (1.0f / 4096.0f);
}

// ---------------------------------------------------------------------------
// Kernel 2: group-64 absmax fake-quantize of x -> fp16 (unchanged).
// ---------------------------------------------------------------------------
__global__ __launch_bounds__(256) void quant_x_kernel(
    const float4* __restrict__ x4, f16x4* __restrict__ xq4)
{
  const int i = blockIdx.x * 256 + threadIdx.x;
  float4 v = x4[i];
  float am = fmaxf(fmaxf(fabsf(v.x), fabsf(v.y)),
                   fmaxf(fabsf(v.z), fabsf(v.w)));
  am = fmaxf(am, __shfl_xor(am, 1));
  am = fmaxf(am, __shfl_xor(am, 2));
  am = fmaxf(am, __shfl_xor(am, 4));
  am = fmaxf(am, __shfl_xor(am, 8));
  const float scale = fmaxf(am, 1e-8f);

  float q0 = fminf(fmaxf(rintf(v.x / scale * 127.0f), -127.0f), 127.0f);
  float q1 = fminf(fmaxf(rintf(v.y / scale * 127.0f), -127.0f), 127.0f);
  float q2 = fminf(fmaxf(rintf(v.z / scale * 127.0f), -127.0f), 127.0f);
  float q3 = fminf(fmaxf(rintf(v.w / scale * 127.0f), -127.0f), 127.0f);

  f16x4 o;
  o[0] = (f16)(q0 * scale / 127.0f);
  o[1] = (f16)(q1 * scale / 127.0f);
  o[2] = (f16)(q2 * scale / 127.0f);
  o[3] = (f16)(q3 * scale / 127.0f);
  xq4[i] = o;
}

// ---------------------------------------------------------------------------
// Kernel 3: 256x256 8-phase GEMM.  C[m,n] = alpha[n] * sum_k A[m,k]*Bt[n,k]
// 8 waves (2M x 4N), BK=64, 128 KiB LDS = 2 tile-buffers x {A0,A1,B0,B1}.
// Swizzle (r3): 3-bit XOR, byte_col ^= (row&7)<<4 — maps the 8 rows of each
// 8-lane issue group onto 8 distinct 16B slots (all 32 banks). Applied on the
// pre-swizzled GLOBAL source (linear gload_lds dest) AND the ds_read address
// (both-sides-or-neither, rule 21). Counted vmcnt(2) at ph4/8; setprio (T5).
// ---------------------------------------------------------------------------
#define BM 256
#define BN 256
#define BK 64

__global__ __launch_bounds__(512, 2) void gemm_kernel(
    const f16* __restrict__ A,        // [M,K] xq
    const f16* __restrict__ Bt,       // [N,K] sgn
    const float* __restrict__ alpha,  // [N]
    float* __restrict__ C, int M, int N, int K)
{
  __shared__ __align__(16) char smem[131072];

  const int tid  = threadIdx.x;
  const int wave = tid >> 6;
  const int lane = tid & 63;
  const int wm = wave >> 2;   // 0..1: which 128-row half of the C tile
  const int wn = wave & 3;    // 0..3: which 64-col strip

  // XCD-aware bijective swizzle (nwg = 512, divisible by 8)
  const int nbx = N / BN;
  const int nwg = gridDim.x;
  const int cpx = nwg >> 3;
  const int bid = blockIdx.x;
  const int swz = (bid & 7) * cpx + (bid >> 3);
  const int bn = (swz % nbx) * BN;
  const int bm = (swz / nbx) * BM;

  // fragment-read addressing. Row stride 128B; col byte = lk*2 + kh*64,
  // XOR'd with (row&7)<<4. row&7 == lrow&7 for every fragment (16-row steps).
  const int lrow = lane & 15;
  const int lk   = (lane >> 4) * 8;
  const int rxor = (lrow & 7) << 4;
  const int colx = (lk * 2) ^ rxor;              // kh=0 column; kh=1 = ^64
  const int aob  = wm * 16384 + lrow * 128 + colx;
  const int bob  = 32768 + (wn >> 1) * 16384 + ((wn & 1) * 64 + lrow) * 128 + colx;

  // staging: lane covers row (lane>>3) of an 8-row chunk, 16B slot (lane&7).
  // linear LDS dest; global source slot = (lane&7) ^ (lane>>3)  (same involution).
  const int srow = lane >> 3;
  const int ksrc = ((lane & 7) ^ srow) * 8;
  const size_t lsoff = (size_t)srow * K + ksrc;

#define RDA(BUF, mi, kh) (*(const f16x8*)(smem + (BUF) + (aob ^ ((kh)*64)) + (mi)*2048))
#define RDB(BUF, ni, kh) (*(const f16x8*)(smem + (BUF) + (bob ^ ((kh)*64)) + (ni)*2048))

  // stage one 128-row x 64-col half-tile: 2 gload16 per wave (16 KiB total)
#define STAGE(LDSOFF, MAT, GROW, T) do {                                        \
    const f16* _s = (MAT) + (size_t)((GROW) + wave * 8) * K + (size_t)(T) * 64; \
    gload16(_s + lsoff, smem + (LDSOFF) + wave * 1024);                         \
    gload16(_s + (size_t)64 * K + lsoff, smem + (LDSOFF) + 8192 + wave * 1024); \
  } while (0)

#define MMQ(AARR, BARR, MBASE) do {                                             \
    _Pragma("unroll")                                                           \
    for (int mi = 0; mi < 4; ++mi) {                                            \
      _Pragma("unroll")                                                         \
      for (int ni = 0; ni < 4; ++ni) {                                          \
        acc[(MBASE) + mi][ni] = __builtin_amdgcn_mfma_f32_16x16x32_f16(         \
            AARR[(MBASE) + mi], BARR[ni], acc[(MBASE) + mi][ni], 0, 0, 0);      \
      }                                                                         \
    }                                                                           \
  } while (0)

  f32x4 acc[8][4] = {};
  f16x8 a0[8], a1[8], bq0[4], bq1[4];

  const int nk = K / BK;  // 64 K-tiles, 2 per iteration

  // prologue: tile0 -> buf0 (4 halves), tile1.B0 -> buf1. vmcnt(2) leaves
  // tile1.B0 in flight = steady-state entry condition.
  STAGE(0,             A,  bm,       0);
  STAGE(16384,         A,  bm + 128, 0);
  STAGE(32768,         Bt, bn,       0);
  STAGE(49152,         Bt, bn + 128, 0);
  STAGE(65536 + 32768, Bt, bn,      1);
  asm volatile("s_waitcnt vmcnt(2)" ::: "memory");
  BAR();

  for (int it = 0; it < nk / 2; ++it) {
    const int t1 = 2 * it + 1;
    int t2 = 2 * it + 2; if (t2 >= nk) t2 -= nk;  // wrapped: harmless overwrite
    int t3 = 2 * it + 3; if (t3 >= nk) t3 -= nk;  // of never-again-read regions

    // ================= tile even (buf0) =================
    // ph1: reads A.k0 (all 8) + B.k0; stage buf1.B1<-t1
#pragma unroll
    for (int mi = 0; mi < 4; ++mi) a0[mi] = RDA(0, mi, 0);
#pragma unroll
    for (int ni = 0; ni < 4; ++ni) bq0[ni] = RDB(0, ni, 0);
#pragma unroll
    for (int mi = 4; mi < 8; ++mi) a0[mi] = RDA(0, mi, 0);
    STAGE(65536 + 49152, Bt, bn + 128, t1);
    BAR();
    __builtin_amdgcn_s_setprio(1);
    MMQ(a0, bq0, 0);
    __builtin_amdgcn_s_setprio(0);
    BAR();

    // ph2: reads A.k1 lo + B.k1; stage buf1.A0<-t1
#pragma unroll
    for (int mi = 0; mi < 4; ++mi) a1[mi] = RDA(0, mi, 1);
#pragma unroll
    for (int ni = 0; ni < 4; ++ni) bq1[ni] = RDB(0, ni, 1);
    STAGE(65536, A, bm, t1);
    BAR();
    __builtin_amdgcn_s_setprio(1);
    MMQ(a0, bq0, 4);
    __builtin_amdgcn_s_setprio(0);
    BAR();

    // ph3: reads A.k1 hi; stage buf1.A1<-t1
#pragma unroll
    for (int mi = 4; mi < 8; ++mi) a1[mi] = RDA(0, mi, 1);
    STAGE(65536 + 16384, A, bm + 128, t1);
    BAR();
    __builtin_amdgcn_s_setprio(1);
    MMQ(a1, bq1, 0);
    __builtin_amdgcn_s_setprio(0);
    BAR();

    // ph4: stage buf0.B0<-t2; counted vmcnt(2): tile1 landed, t2.B0 in flight.
    STAGE(32768, Bt, bn, t2);
    asm volatile("s_waitcnt vmcnt(2)" ::: "memory");
    BAR();
    __builtin_amdgcn_s_setprio(1);
    MMQ(a1, bq1, 4);
    __builtin_amdgcn_s_setprio(0);
    BAR();

    // ================= tile odd (buf1) =================
    // ph5
#pragma unroll
    for (int mi = 0; mi < 4; ++mi) a0[mi] = RDA(65536, mi, 0);
#pragma unroll
    for (int ni = 0; ni < 4; ++ni) bq0[ni] = RDB(65536, ni, 0);
#pragma unroll
    for (int mi = 4; mi < 8; ++mi) a0[mi] = RDA(65536, mi, 0);
    STAGE(49152, Bt, bn + 128, t2);
    BAR();
    __builtin_amdgcn_s_setprio(1);
    MMQ(a0, bq0, 0);
    __builtin_amdgcn_s_setprio(0);
    BAR();

    // ph6
#pragma unroll
    for (int mi = 0; mi < 4; ++mi) a1[mi] = RDA(65536, mi, 1);
#pragma unroll
    for (int ni = 0; ni < 4; ++ni) bq1[ni] = RDB(65536, ni, 1);
    STAGE(0, A, bm, t2);
    BAR();
    __builtin_amdgcn_s_setprio(1);
    MMQ(a0, bq0, 4);
    __builtin_amdgcn_s_setprio(0);
    BAR();

    // ph7
#pragma unroll
    for (int mi = 4; mi < 8; ++mi) a1[mi] = RDA(65536, mi, 1);
    STAGE(16384, A, bm + 128, t2);
    BAR();
    __builtin_amdgcn_s_setprio(1);
    MMQ(a1, bq1, 0);
    __builtin_amdgcn_s_setprio(0);
    BAR();

    // ph8: stage buf1.B0<-t3; counted vmcnt(2): t2 fully landed.
    STAGE(65536 + 32768, Bt, bn, t3);
    asm volatile("s_waitcnt vmcnt(2)" ::: "memory");
    BAR();
    __builtin_amdgcn_s_setprio(1);
    MMQ(a1, bq1, 4);
    __builtin_amdgcn_s_setprio(0);
    BAR();
  }

  // epilogue: C = acc * alpha[n]; C/D layout col=lane&15, row=(lane>>4)*4+r
  const int r0 = bm + wm * 128 + ((lane >> 4) << 2);
  const int c0 = bn + wn * 64 + (lane & 15);
#pragma unroll
  for (int ni = 0; ni < 4; ++ni) {
    const int n = c0 + ni * 16;
    const float alv = alpha[n];
#pragma unroll
    for (int mi = 0; mi < 8; ++mi) {
#pragma unroll
      for (int r = 0; r < 4; ++r) {
        C[(size_t)(r0 + mi * 16 + r) * N + n] = acc[mi][ni][r] * alv;
      }
    }
  }
}

// ---------------------------------------------------------------------------
extern "C" void kernel_launch(void* const* d_in, const int* in_sizes, int n_in,
                              void* d_out, int out_size, void* d_ws, size_t ws_size,
                              hipStream_t stream) {
  const float* x = (const float*)d_in[0];  // [M, K] fp32
  const float* W = (const float*)d_in[1];  // [N, K] fp32
  float* y = (float*)d_out;                // [M, N] fp32

  const int K = 4096;
  const int M = in_sizes[0] / K;           // 8192
  const int N = in_sizes[1] / K;           // 4096

  f16*   xq    = (f16*)d_ws;
  f16*   sgn   = (f16*)((char*)d_ws + (size_t)M * K * 2);
  float* alpha = (float*)((char*)d_ws + (size_t)M * K * 2 + (size_t)N * K * 2);

  prep_w_kernel<<<N, 256, 0, stream>>>(W, sgn, alpha, K);

  const int n4 = (M * K) / 4;
  quant_x_kernel<<<n4 / 256, 256, 0, stream>>>((const float4*)x, (f16x4*)xq);

  const int nblk = (M / BM) * (N / BN);    // 512, divisible by 8
  gemm_kernel<<<nblk, 512, 0, stream>>>(xq, sgn, alpha, y, M, N, K);
}

// Round 4
// 473.671 us; speedup vs baseline: 1.2182x; 1.0465x over previous
//
#include <hip/hip_runtime.h>
#include <hip/hip_bf16.h>
#include <stdint.h>
#include <stddef.h>

typedef _Float16 f16;
typedef _Float16 f16x4 __attribute__((ext_vector_type(4)));
typedef _Float16 f16x8 __attribute__((ext_vector_type(8)));
typedef float    f32x4 __attribute__((ext_vector_type(4)));

// async global->LDS, 16B per lane. LDS dest = wave-uniform base + lane*16.
__device__ __forceinline__ void gload16(const void* g, void* l) {
  __builtin_amdgcn_global_load_lds(
      (__attribute__((address_space(1))) void*)g,
      (__attribute__((address_space(3))) void*)l,
      16, 0, 0);
}

// ---------------------------------------------------------------------------
// Kernel 1: per-row W prep (unchanged, known-good).
// ---------------------------------------------------------------------------
__global__ __launch_bounds__(256) void prep_w_kernel(
    const float* __restrict__ W, f16* __restrict__ sgn,
    float* __restrict__ alpha, int K)
{
  const int row = blockIdx.x;
  const int tid = threadIdx.x;
  const float4* Wr = (const float4*)(W + (size_t)row * K);

  float4 v[4];
#pragma unroll
  for (int j = 0; j < 4; ++j) v[j] = Wr[j * 256 + tid];

  __shared__ float red1[4];
  __shared__ float red2[4];

  float s = 0.f;
#pragma unroll
  for (int j = 0; j < 4; ++j) s += (v[j].x + v[j].y) + (v[j].z + v[j].w);
#pragma unroll
  for (int m = 32; m >= 1; m >>= 1) s += __shfl_xor(s, m);
  if ((tid & 63) == 0) red1[tid >> 6] = s;
  __syncthreads();
  const float mean = (red1[0] + red1[1] + red1[2] + red1[3]) * (1.0f / 4096.0f);

  float a = 0.f;
#pragma unroll
  for (int j = 0; j < 4; ++j) {
    a += fabsf(v[j].x - mean) + fabsf(v[j].y - mean) +
         fabsf(v[j].z - mean) + fabsf(v[j].w - mean);
  }
#pragma unroll
  for (int m = 32; m >= 1; m >>= 1) a += __shfl_xor(a, m);
  if ((tid & 63) == 0) red2[tid >> 6] = a;

  f16x4* so = (f16x4*)(sgn + (size_t)row * K);
#pragma unroll
  for (int j = 0; j < 4; ++j) {
    float w0 = v[j].x - mean, w1 = v[j].y - mean,
          w2 = v[j].z - mean, w3 = v[j].w - mean;
    f16x4 o;
    o[0] = (f16)((w0 > 0.f) ? 1.f : ((w0 < 0.f) ? -1.f : 0.f));
    o[1] = (f16)((w1 > 0.f) ? 1.f : ((w1 < 0.f) ? -1.f : 0.f));
    o[2] = (f16)((w2 > 0.f) ? 1.f : ((w2 < 0.f) ? -1.f : 0.f));
    o[3] = (f16)((w3 > 0.f) ? 1.f : ((w3 < 0.f) ? -1.f : 0.f));
    so[j * 256 + tid] = o;
  }
  __syncthreads();
  if (tid == 0)
    alpha[row] = (red2[0] + red2[1] + red2[2] + red2[3]) * (1.0f / 4096.0f);
}

// ---------------------------------------------------------------------------
// Kernel 2: group-64 absmax fake-quantize of x -> fp16 (unchanged).
// ---------------------------------------------------------------------------
__global__ __launch_bounds__(256) void quant_x_kernel(
    const float4* __restrict__ x4, f16x4* __restrict__ xq4)
{
  const int i = blockIdx.x * 256 + threadIdx.x;
  float4 v = x4[i];
  float am = fmaxf(fmaxf(fabsf(v.x), fabsf(v.y)),
                   fmaxf(fabsf(v.z), fabsf(v.w)));
  am = fmaxf(am, __shfl_xor(am, 1));
  am = fmaxf(am, __shfl_xor(am, 2));
  am = fmaxf(am, __shfl_xor(am, 4));
  am = fmaxf(am, __shfl_xor(am, 8));
  const float scale = fmaxf(am, 1e-8f);

  float q0 = fminf(fmaxf(rintf(v.x / scale * 127.0f), -127.0f), 127.0f);
  float q1 = fminf(fmaxf(rintf(v.y / scale * 127.0f), -127.0f), 127.0f);
  float q2 = fminf(fmaxf(rintf(v.z / scale * 127.0f), -127.0f), 127.0f);
  float q3 = fminf(fmaxf(rintf(v.w / scale * 127.0f), -127.0f), 127.0f);

  f16x4 o;
  o[0] = (f16)(q0 * scale / 127.0f);
  o[1] = (f16)(q1 * scale / 127.0f);
  o[2] = (f16)(q2 * scale / 127.0f);
  o[3] = (f16)(q3 * scale / 127.0f);
  xq4[i] = o;
}

// ---------------------------------------------------------------------------
// Kernel 3: 256x256 GEMM, frag-double-buffered 1-barrier-per-K-tile schedule.
//   C[m,n] = alpha[n] * sum_k A[m,k] * Bt[n,k]
// 8 waves (2M x 4N), BK=64, 128 KiB LDS = 2 tile buffers x {A0,A1,B0,B1}.
// Per iteration t (tile t in buf b=t&1):
//   1. ds_read (t,k1)    -> fn            (LDS pipe drains under step 2)
//   2. MFMA fc (k0)                       (32 mfma)
//   3. lgkmcnt(0); vmcnt(0); s_barrier    (reads drained; tile t+1 landed)
//   4. ds_read (t+1,k0)  -> fc            (from buf b^1)
//   5. STAGE tile t+2 -> buf b            (8 gload16, fly a full iteration)
//   6. MFMA fn (k1)                       (hides step 4/5 latency)
// Swizzle: byte_col ^= (row&7)<<4 on both stage-source and ds_read (rule 21).
// ---------------------------------------------------------------------------
#define BM 256
#define BN 256
#define BK 64

__global__ __launch_bounds__(512, 2) void gemm_kernel(
    const f16* __restrict__ A,        // [M,K] xq
    const f16* __restrict__ Bt,       // [N,K] sgn
    const float* __restrict__ alpha,  // [N]
    float* __restrict__ C, int M, int N, int K)
{
  __shared__ __align__(16) char smem[131072];

  const int tid  = threadIdx.x;
  const int wave = tid >> 6;
  const int lane = tid & 63;
  const int wm = wave >> 2;   // 0..1: which 128-row half of the C tile
  const int wn = wave & 3;    // 0..3: which 64-col strip

  // XCD-aware bijective swizzle (nwg = 512, divisible by 8)
  const int nbx = N / BN;
  const int nwg = gridDim.x;
  const int cpx = nwg >> 3;
  const int bid = blockIdx.x;
  const int swz = (bid & 7) * cpx + (bid >> 3);
  const int bn = (swz % nbx) * BN;
  const int bm = (swz / nbx) * BM;

  // fragment-read addressing. Row stride 128B; col byte = lk*2 + kh*64,
  // XOR'd with (row&7)<<4. row&7 == lrow&7 for every fragment (16-row steps).
  const int lrow = lane & 15;
  const int lk   = (lane >> 4) * 8;
  const int rxor = (lrow & 7) << 4;
  const int colx = (lk * 2) ^ rxor;              // kh=0 column; kh=1 = ^64
  const int aob  = wm * 16384 + lrow * 128 + colx;
  const int bob  = 32768 + (wn >> 1) * 16384 + ((wn & 1) * 64 + lrow) * 128 + colx;

  // staging: lane covers row (lane>>3) of an 8-row chunk, 16B slot (lane&7).
  // linear LDS dest; global source slot = (lane&7) ^ (lane>>3) (same involution).
  const int srow = lane >> 3;
  const int ksrc = ((lane & 7) ^ srow) * 8;
  const size_t lsoff = (size_t)srow * K + ksrc;

#define RDA(BUF, mi, kh) (*(const f16x8*)(smem + (BUF) + (aob ^ ((kh)*64)) + (mi)*2048))
#define RDB(BUF, ni, kh) (*(const f16x8*)(smem + (BUF) + (bob ^ ((kh)*64)) + (ni)*2048))

  // stage one 128-row x 64-col half-tile: 2 gload16 per wave (16 KiB total)
#define STAGE(LDSOFF, MAT, GROW, T) do {                                        \
    const f16* _s = (MAT) + (size_t)((GROW) + wave * 8) * K + (size_t)(T) * 64; \
    gload16(_s + lsoff, smem + (LDSOFF) + wave * 1024);                         \
    gload16(_s + (size_t)64 * K + lsoff, smem + (LDSOFF) + 8192 + wave * 1024); \
  } while (0)

#define STAGE_TILE(BUF, T) do {                                                 \
    STAGE((BUF) +     0, A,  bm,       (T));                                    \
    STAGE((BUF) + 16384, A,  bm + 128, (T));                                    \
    STAGE((BUF) + 32768, Bt, bn,       (T));                                    \
    STAGE((BUF) + 49152, Bt, bn + 128, (T));                                    \
  } while (0)

#define MM32(AF, BF) do {                                                       \
    _Pragma("unroll")                                                           \
    for (int mi = 0; mi < 8; ++mi) {                                            \
      _Pragma("unroll")                                                         \
      for (int ni = 0; ni < 4; ++ni) {                                          \
        acc[mi][ni] = __builtin_amdgcn_mfma_f32_16x16x32_f16(                   \
            AF[mi], BF[ni], acc[mi][ni], 0, 0, 0);                              \
      }                                                                         \
    }                                                                           \
  } while (0)

  f32x4 acc[8][4] = {};
  f16x8 fcA[8], fcB[4], fnA[8], fnB[4];

  const int nk = K / BK;  // 64 K-tiles

  // prologue: tile0 -> buf0, tile1 -> buf1; wait tile0 only (tile1 flies).
  STAGE_TILE(0, 0);
  STAGE_TILE(65536, 1);
  asm volatile("s_waitcnt vmcnt(8)" ::: "memory");
  __builtin_amdgcn_sched_barrier(0);
  __builtin_amdgcn_s_barrier();
  asm volatile("" ::: "memory");

  // fc <- (0, k0)
#pragma unroll
  for (int mi = 0; mi < 8; ++mi) fcA[mi] = RDA(0, mi, 0);
#pragma unroll
  for (int ni = 0; ni < 4; ++ni) fcB[ni] = RDB(0, ni, 0);

  for (int t = 0; t < nk - 1; ++t) {
    const int b  = (t & 1) ? 65536 : 0;
    const int nb = 65536 - b;

    // 1. fn <- (t, k1)  — drains under step 2's MFMA
#pragma unroll
    for (int mi = 0; mi < 8; ++mi) fnA[mi] = RDA(b, mi, 1);
#pragma unroll
    for (int ni = 0; ni < 4; ++ni) fnB[ni] = RDB(b, ni, 1);

    // 2. MFMA k0
    __builtin_amdgcn_s_setprio(1);
    MM32(fcA, fcB);
    __builtin_amdgcn_s_setprio(0);

    // 3. my reads drained + my stages of t+1 landed; barrier -> ALL waves' are
    asm volatile("s_waitcnt lgkmcnt(0)" ::: "memory");
    asm volatile("s_waitcnt vmcnt(0)" ::: "memory");
    __builtin_amdgcn_sched_barrier(0);
    __builtin_amdgcn_s_barrier();
    asm volatile("" ::: "memory");

    // 4. fc <- (t+1, k0) from the other buffer — drains under step 6's MFMA
#pragma unroll
    for (int mi = 0; mi < 8; ++mi) fcA[mi] = RDA(nb, mi, 0);
#pragma unroll
    for (int ni = 0; ni < 4; ++ni) fcB[ni] = RDB(nb, ni, 0);

    // 5. stage tile t+2 into buf b (reads of buf b drained pre-barrier).
    //    wrapped index for the last iterations: harmless overwrite of a
    //    buffer that is never read again.
    int t2 = t + 2; if (t2 >= nk) t2 -= nk;
    STAGE_TILE(b, t2);

    // 6. MFMA k1
    __builtin_amdgcn_s_setprio(1);
    MM32(fnA, fnB);
    __builtin_amdgcn_s_setprio(0);
  }

  // peeled last tile (t = nk-1, buf1): no more staging/barriers needed.
#pragma unroll
  for (int mi = 0; mi < 8; ++mi) fnA[mi] = RDA(65536, mi, 1);
#pragma unroll
  for (int ni = 0; ni < 4; ++ni) fnB[ni] = RDB(65536, ni, 1);
  __builtin_amdgcn_s_setprio(1);
  MM32(fcA, fcB);
  MM32(fnA, fnB);
  __builtin_amdgcn_s_setprio(0);

  // epilogue: C = acc * alpha[n]; C/D layout col=lane&15, row=(lane>>4)*4+r
  const int r0 = bm + wm * 128 + ((lane >> 4) << 2);
  const int c0 = bn + wn * 64 + (lane & 15);
#pragma unroll
  for (int ni = 0; ni < 4; ++ni) {
    const int n = c0 + ni * 16;
    const float alv = alpha[n];
#pragma unroll
    for (int mi = 0; mi < 8; ++mi) {
#pragma unroll
      for (int r = 0; r < 4; ++r) {
        C[(size_t)(r0 + mi * 16 + r) * N + n] = acc[mi][ni][r] * alv;
      }
    }
  }
}

// ---------------------------------------------------------------------------
extern "C" void kernel_launch(void* const* d_in, const int* in_sizes, int n_in,
                              void* d_out, int out_size, void* d_ws, size_t ws_size,
                              hipStream_t stream) {
  const float* x = (const float*)d_in[0];  // [M, K] fp32
  const float* W = (const float*)d_in[1];  // [N, K] fp32
  float* y = (float*)d_out;                // [M, N] fp32

  const int K = 4096;
  const int M = in_sizes[0] / K;           // 8192
  const int N = in_sizes[1] / K;           // 4096

  f16*   xq    = (f16*)d_ws;
  f16*   sgn   = (f16*)((char*)d_ws + (size_t)M * K * 2);
  float* alpha = (float*)((char*)d_ws + (size_t)M * K * 2 + (size_t)N * K * 2);

  prep_w_kernel<<<N, 256, 0, stream>>>(W, sgn, alpha, K);

  const int n4 = (M * K) / 4;
  quant_x_kernel<<<n4 / 256, 256, 0, stream>>>((const float4*)x, (f16x4*)xq);

  const int nblk = (M / BM) * (N / BN);    // 512, divisible by 8
  gemm_kernel<<<nblk, 512, 0, stream>>>(xq, sgn, alpha, y, M, N, K);
}